// Round 3
// baseline (183.700 us; speedup 1.0000x reference)
//
#include <hip/hip_runtime.h>

typedef float v2f __attribute__((ext_vector_type(2)));

namespace {

constexpr int Tn = 1000;   // time steps
constexpr int Fn = 22;     // input features
constexpr int Hn = 10;     // hidden
constexpr int Cn = 4;      // classes

__device__ __forceinline__ v2f fma2(v2f a, v2f b, v2f c) {
    return __builtin_elementwise_fma(a, b, c);
}
__device__ __forceinline__ v2f mk2(float a, float b) { v2f r; r.x = a; r.y = b; return r; }
__device__ __forceinline__ float bperm(int addr, float v) {
    return __int_as_float(__builtin_amdgcn_ds_bpermute(addr, __float_as_int(v)));
}
__device__ __forceinline__ void sfence() { __builtin_amdgcn_sched_barrier(0); }

__global__ __launch_bounds__(64, 1) void rnn_fused(
    const float* __restrict__ x,
    const float* __restrict__ w_ih0, const float* __restrict__ w_hh0,
    const float* __restrict__ b_ih0, const float* __restrict__ b_hh0,
    const float* __restrict__ w_ih1, const float* __restrict__ w_hh1,
    const float* __restrict__ b_ih1, const float* __restrict__ b_hh1,
    const float* __restrict__ w_lin, const float* __restrict__ b_lin,
    float* __restrict__ out)
{
    const int lane = threadIdx.x;          // one wave per block
    const int g    = lane >> 4;            // 16-lane group -> one batch
    const int j    = lane & 15;            // neuron id within group
    const int b    = blockIdx.x * 4 + g;
    const int jr   = (j < Hn) ? j : 0;
    const int jc   = (j < Cn) ? j : 0;
    const int pb   = (lane & 48) << 2;     // byte addr of group's lane 0

    int bpa[Hn];
    #pragma unroll
    for (int k = 0; k < Hn; ++k) bpa[k] = pb + (k << 2);

    // ---- weights ----
    v2f wih0p[11];
    #pragma unroll
    for (int p = 0; p < 11; ++p)
        wih0p[p] = mk2(w_ih0[jr * Fn + 2 * p], w_ih0[jr * Fn + 2 * p + 1]);
    float whh0[Hn], wih1[Hn], whh1[Hn], wlin[Hn];
    #pragma unroll
    for (int k = 0; k < Hn; ++k) {
        whh0[k] = w_hh0[jr * Hn + k];
        wih1[k] = w_ih1[jr * Hn + k];
        whh1[k] = w_hh1[jr * Hn + k];
        wlin[k] = w_lin[jc * Hn + k];
    }
    const v2f  bz    = mk2(b_ih0[jr] + b_hh0[jr], 0.f);  // bias1 folded into z
    const float bias2 = b_ih1[jr] + b_hh1[jr];
    const float blv   = b_lin[jc];

    const float* xrow = x + (size_t)b * (Tn * Fn);

    // ---- x register sets: xv[(t%3)*11 + p] ----
    v2f xv[33];
    #pragma unroll
    for (int k = 0; k < 3; ++k)
        #pragma unroll
        for (int p = 0; p < 11; ++p)
            xv[k * 11 + p] = *(const v2f*)(xrow + k * Fn + 2 * p);

    // broadcast state: p1 = h1(t-1), p2 = h2(t-2); zero before t=0
    float p1[Hn], p2[Hn];
    #pragma unroll
    for (int k = 0; k < Hn; ++k) { p1[k] = 0.f; p2[k] = 0.f; }

    // carried z = bias1 + x(t).w_ih0 (unreduced pk pairs)
    v2f zA, zB;
    auto zcomp = [&](int zi) {
        zA = fma2(xv[zi + 0], wih0p[0], bz);
        zB = xv[zi + 1] * wih0p[1];
        zA = fma2(xv[zi + 2],  wih0p[2],  zA);
        zB = fma2(xv[zi + 3],  wih0p[3],  zB);
        zA = fma2(xv[zi + 4],  wih0p[4],  zA);
        zB = fma2(xv[zi + 5],  wih0p[5],  zB);
        zA = fma2(xv[zi + 6],  wih0p[6],  zA);
        zB = fma2(xv[zi + 7],  wih0p[7],  zB);
        zA = fma2(xv[zi + 8],  wih0p[8],  zA);
        zB = fma2(xv[zi + 9],  wih0p[9],  zB);
        zA = fma2(xv[zi + 10], wih0p[10], zA);
    };
    zcomp(0);  // z(0)

    // ---- skewed step: L1(t) then L2(t-1) ----
    //  zi: xv base for z(t+1); do_z: compute it
    //  li: xv base receiving x(t+3) (-1 = skip); laddr: its address
    //  do_l2: run L2(t-1) (false only at t=0)
    auto step = [&](int zi, bool do_z, int li, const float* laddr, bool do_l2) {
        // --- L1(t): consume p1 = h1(t-1)  [lgkm wait lands here]
        float c0 = fmaf(p1[0], whh0[0], zA.x);
        float c1 = fmaf(p1[1], whh0[1], zA.y);
        float c2 = fmaf(p1[2], whh0[2], zB.x);
        float c3 = fmaf(p1[3], whh0[3], zB.y);
        c0 = fmaf(p1[4], whh0[4], c0);
        c1 = fmaf(p1[5], whh0[5], c1);
        c2 = fmaf(p1[6], whh0[6], c2);
        c3 = fmaf(p1[7], whh0[7], c3);
        c0 = fmaf(p1[8], whh0[8], c0);
        c1 = fmaf(p1[9], whh0[9], c1);
        const float h1n = fmaxf((c0 + c1) + (c2 + c3), 0.f);

        // --- issue bp1(h1(t)); consumed at L1(t+1)
        float np1[Hn];
        #pragma unroll
        for (int k = 0; k < Hn; ++k) np1[k] = bperm(bpa[k], h1n);
        sfence();

        if (do_l2) {
            // --- L2(t-1) ih-part: uses OLD p1 = h1(t-1), no new deps
            float d0 = fmaf(p1[0], wih1[0], bias2);
            float d1 = p1[1] * wih1[1];
            float d2 = p1[2] * wih1[2];
            float d3 = p1[3] * wih1[3];
            d0 = fmaf(p1[4], wih1[4], d0);
            d1 = fmaf(p1[5], wih1[5], d1);
            d2 = fmaf(p1[6], wih1[6], d2);
            d3 = fmaf(p1[7], wih1[7], d3);
            d0 = fmaf(p1[8], wih1[8], d0);
            d1 = fmaf(p1[9], wih1[9], d1);

            // --- x prefetch (filler before the p2 wait)
            if (li >= 0) {
                #pragma unroll
                for (int p = 0; p < 11; ++p)
                    xv[li + p] = *(const v2f*)(laddr + 2 * p);
            }

            // --- hh-part: consume p2 = h2(t-2)  [lgkm wait lands here]
            d0 = fmaf(p2[0], whh1[0], d0);
            d1 = fmaf(p2[1], whh1[1], d1);
            d2 = fmaf(p2[2], whh1[2], d2);
            d3 = fmaf(p2[3], whh1[3], d3);
            d0 = fmaf(p2[4], whh1[4], d0);
            d1 = fmaf(p2[5], whh1[5], d1);
            d2 = fmaf(p2[6], whh1[6], d2);
            d3 = fmaf(p2[7], whh1[7], d3);
            d0 = fmaf(p2[8], whh1[8], d0);
            d1 = fmaf(p2[9], whh1[9], d1);
            const float h2n = fmaxf((d0 + d1) + (d2 + d3), 0.f);

            // --- issue bp2(h2(t-1)); consumed at L2(t) hh-part
            #pragma unroll
            for (int k = 0; k < Hn; ++k) p2[k] = bperm(bpa[k], h2n);
            sfence();
        } else if (li >= 0) {
            #pragma unroll
            for (int p = 0; p < 11; ++p)
                xv[li + p] = *(const v2f*)(laddr + 2 * p);
        }

        // commit new h1 broadcast (SSA rename)
        #pragma unroll
        for (int k = 0; k < Hn; ++k) p1[k] = np1[k];

        // --- z(t+1) (filler tail; also covers both RT gaps via wrap-around)
        if (do_z) zcomp(zi);
    };

    // ---- t = 0 (no L2 yet; load x(3) -> set 0; z(1) from set 1) ----
    step(11, true, 0, xrow + 3 * Fn, false);

    // ---- main loop: t = 1+6c+s, c = 0..165, s = 0..5  (t = 1..996) ----
    const float* xp = xrow + Fn;
    for (int c = 0; c < 166; ++c) {
        step(22, true, 11, xp + 3 * Fn, true);   // s=0: t%3=1
        step( 0, true, 22, xp + 4 * Fn, true);   // s=1: t%3=2
        step(11, true,  0, xp + 5 * Fn, true);   // s=2: t%3=0
        step(22, true, 11, xp + 6 * Fn, true);   // s=3: t%3=1
        step( 0, true, 22, xp + 7 * Fn, true);   // s=4: t%3=2
        step(11, true,  0, xp + 8 * Fn, true);   // s=5: t%3=0
        xp += 6 * Fn;
    }

    // ---- tail: t = 997, 998, 999 (no more x loads) ----
    step(22, true,  -1, nullptr, true);   // t=997: z(998) from set 2
    step( 0, true,  -1, nullptr, true);   // t=998: z(999) from set 0
    step( 0, false, -1, nullptr, true);   // t=999: no z

    // ---- epilogue: L2(999) ----
    {
        float d0 = fmaf(p1[0], wih1[0], bias2);
        float d1 = p1[1] * wih1[1];
        float d2 = p1[2] * wih1[2];
        float d3 = p1[3] * wih1[3];
        d0 = fmaf(p1[4], wih1[4], d0);
        d1 = fmaf(p1[5], wih1[5], d1);
        d2 = fmaf(p1[6], wih1[6], d2);
        d3 = fmaf(p1[7], wih1[7], d3);
        d0 = fmaf(p1[8], wih1[8], d0);
        d1 = fmaf(p1[9], wih1[9], d1);
        d0 = fmaf(p2[0], whh1[0], d0);
        d1 = fmaf(p2[1], whh1[1], d1);
        d2 = fmaf(p2[2], whh1[2], d2);
        d3 = fmaf(p2[3], whh1[3], d3);
        d0 = fmaf(p2[4], whh1[4], d0);
        d1 = fmaf(p2[5], whh1[5], d1);
        d2 = fmaf(p2[6], whh1[6], d2);
        d3 = fmaf(p2[7], whh1[7], d3);
        d0 = fmaf(p2[8], whh1[8], d0);
        d1 = fmaf(p2[9], whh1[9], d1);
        const float h2n = fmaxf((d0 + d1) + (d2 + d3), 0.f);

        // broadcast h2(999) and compute the linear head
        float ph[Hn];
        #pragma unroll
        for (int k = 0; k < Hn; ++k) ph[k] = bperm(bpa[k], h2n);

        if (j < Cn) {
            float o = blv;
            #pragma unroll
            for (int k = 0; k < Hn; ++k) o = fmaf(ph[k], wlin[k], o);
            out[b * Cn + j] = o;
        }
    }
}

} // namespace

extern "C" void kernel_launch(void* const* d_in, const int* in_sizes, int n_in,
                              void* d_out, int out_size, void* d_ws, size_t ws_size,
                              hipStream_t stream) {
    const float* x     = (const float*)d_in[0];
    const float* w_ih0 = (const float*)d_in[1];
    const float* w_hh0 = (const float*)d_in[2];
    const float* b_ih0 = (const float*)d_in[3];
    const float* b_hh0 = (const float*)d_in[4];
    const float* w_ih1 = (const float*)d_in[5];
    const float* w_hh1 = (const float*)d_in[6];
    const float* b_ih1 = (const float*)d_in[7];
    const float* b_hh1 = (const float*)d_in[8];
    const float* w_lin = (const float*)d_in[9];
    const float* b_lin = (const float*)d_in[10];
    float* out = (float*)d_out;

    rnn_fused<<<dim3(256), dim3(64), 0, stream>>>(
        x, w_ih0, w_hh0, b_ih0, b_hh0,
        w_ih1, w_hh1, b_ih1, b_hh1, w_lin, b_lin, out);
}

// Round 4
// 165.102 us; speedup vs baseline: 1.1126x; 1.1126x over previous
//
#include <hip/hip_runtime.h>

typedef float v2f __attribute__((ext_vector_type(2)));

namespace {

constexpr int Tn = 1000, Fn = 22, Hn = 10, Cn = 4;
constexpr int ROWB = Tn * Fn * 4;        // 88000 bytes per batch row
constexpr int CH_STEPS = 32;             // time steps per staged chunk
constexpr int CH_FLOATS = CH_STEPS * Fn; // 704 floats = 2816 B = 11 x 256 B
constexpr int CH_BYTES = CH_FLOATS * 4;
constexpr int NSTAGE = CH_BYTES / 256;   // 11 global_load_lds per chunk

__device__ __forceinline__ v2f mk2(float a, float b) { v2f r; r.x = a; r.y = b; return r; }
__device__ __forceinline__ v2f fma2(v2f a, v2f b, v2f c) { return __builtin_elementwise_fma(a, b, c); }
__device__ __forceinline__ float rlane(float v, int l) {
    return __uint_as_float(__builtin_amdgcn_readlane(__float_as_uint(v), l));
}
__device__ __forceinline__ void gld_lds4(const float* g, float* l) {
    __builtin_amdgcn_global_load_lds(
        (const __attribute__((address_space(1))) unsigned int*)g,
        (__attribute__((address_space(3))) unsigned int*)l, 4, 0, 0);
}

__global__ __launch_bounds__(64, 1) void rnn_fat(
    const float* __restrict__ x,
    const float* __restrict__ w_ih0, const float* __restrict__ w_hh0,
    const float* __restrict__ b_ih0, const float* __restrict__ b_hh0,
    const float* __restrict__ w_ih1, const float* __restrict__ w_hh1,
    const float* __restrict__ b_ih1, const float* __restrict__ b_hh1,
    const float* __restrict__ w_lin, const float* __restrict__ b_lin,
    float* __restrict__ out)
{
    // two DISTINCT LDS objects (not one ring) so the compiler's LDS-DMA alias
    // tracking never ties a ds_read to the chunk currently being DMA-staged.
    __shared__ __align__(16) float chunkA[CH_FLOATS];
    __shared__ __align__(16) float chunkB[CH_FLOATS];

    const int lane = threadIdx.x;          // one wave per block, one BATCH per wave
    const int b    = blockIdx.x;
    const bool isL1 = lane < Hn;                       // lanes 0..9  : layer-1 neurons
    const bool isL2 = (lane >= 16) && (lane < 16 + Hn);// lanes 16..25: layer-2 neurons
    const int j1 = isL1 ? lane : 0;
    const int j2 = isL2 ? (lane - 16) : 0;

    const float* __restrict__ xrow = x + (size_t)b * (Tn * Fn);

    // ---- per-lane weights ----
    v2f wih0p[11];
    #pragma unroll
    for (int p = 0; p < 11; ++p)
        wih0p[p] = mk2(w_ih0[j1 * Fn + 2 * p], w_ih0[j1 * Fn + 2 * p + 1]);
    const float* pa = isL1 ? (w_hh0 + j1 * Hn) : (w_ih1 + j2 * Hn);
    float wa[Hn], wb[Hn];
    #pragma unroll
    for (int k = 0; k < Hn; ++k) wa[k] = pa[k];
    #pragma unroll
    for (int k = 0; k < Hn; ++k) wb[k] = isL2 ? w_hh1[j2 * Hn + k] : 0.f;
    const float bias1 = b_ih0[j1] + b_hh0[j1];
    const float bias2 = b_ih1[j2] + b_hh1[j2];
    const v2f bz = mk2(bias1, 0.f);

    // ---- chunk staging: global -> LDS, 11 x 256B, row-end clamped ----
    auto stage = [&](int c, float* dst) {
        const float* src = xrow + c * CH_FLOATS;
        #pragma unroll
        for (int k = 0; k < NSTAGE; ++k) {
            const int off = c * CH_BYTES + k * 256;
            if (off + 256 <= ROWB) {
                gld_lds4(src + k * 64 + lane, dst + k * 64);
            } else if (off < ROWB) {
                if (lane * 4 < ROWB - off) gld_lds4(src + k * 64 + lane, dst + k * 64);
            } // fully-OOB instrs skipped; unstaged LDS bytes only feed t>=1000 garbage
        }
    };
    stage(0, chunkA);   // chunk 0: t = 0..31

    // ---- x(0), x(1) direct (uniform-address global loads) ----
    v2f xv[2][11];
    v2f t0[11];
    #pragma unroll
    for (int p = 0; p < 11; ++p) t0[p] = ((const v2f*)xrow)[p];
    #pragma unroll
    for (int p = 0; p < 11; ++p) xv[1][p] = ((const v2f*)(xrow + Fn))[p];

    auto zfrom = [&](const v2f* xp) -> float {
        v2f zA = fma2(xp[0], wih0p[0], bz);
        v2f zB = xp[1] * wih0p[1];
        zA = fma2(xp[2], wih0p[2], zA);   zB = fma2(xp[3], wih0p[3], zB);
        zA = fma2(xp[4], wih0p[4], zA);   zB = fma2(xp[5], wih0p[5], zB);
        zA = fma2(xp[6], wih0p[6], zA);   zB = fma2(xp[7], wih0p[7], zB);
        zA = fma2(xp[8], wih0p[8], zA);   zB = fma2(xp[9], wih0p[9], zB);
        zA = fma2(xp[10], wih0p[10], zA);
        return (zA.x + zB.x) + (zA.y + zB.y);
    };

    float zsum = zfrom(t0);   // z(0), valid on L1 lanes

    // h-state, wave-uniform (SGPRs via readlane): S1 = h1(t-1), S2 = h2(t-2)
    float S1[Hn], S2[Hn];
    #pragma unroll
    for (int k = 0; k < Hn; ++k) { S1[k] = 0.f; S2[k] = 0.f; }

    asm volatile("s_waitcnt vmcnt(0)" ::: "memory");   // chunk 0 (and x0/x1) ready
    stage(1, chunkB);                                  // chunk 1: t = 32..63

    // ---- one iteration: L1(t) on lanes 0-9, L2(t-1) on lanes 16-25, uniform ----
    //  q: parity (xv set written by this iter's ds_read of x(t+2))
    //  xr: LDS pointer for x(t+2) (null = skip);  doZ: compute z(t+1)
    auto iter = [&](int q, const float* xr, bool doZ, bool commitS2) {
        float base = isL1 ? zsum : bias2;
        float a0 = fmaf(S1[0], wa[0], base);
        float a1 = S1[1] * wa[1];
        float a2 = S1[2] * wa[2];
        float a3 = S1[3] * wa[3];
        a0 = fmaf(S1[4], wa[4], a0);  a1 = fmaf(S1[5], wa[5], a1);
        a2 = fmaf(S1[6], wa[6], a2);  a3 = fmaf(S1[7], wa[7], a3);
        a0 = fmaf(S1[8], wa[8], a0);  a1 = fmaf(S1[9], wa[9], a1);
        a2 = fmaf(S2[0], wb[0], a2);  a3 = fmaf(S2[1], wb[1], a3);
        a0 = fmaf(S2[2], wb[2], a0);  a1 = fmaf(S2[3], wb[3], a1);
        a2 = fmaf(S2[4], wb[4], a2);  a3 = fmaf(S2[5], wb[5], a3);
        a0 = fmaf(S2[6], wb[6], a0);  a1 = fmaf(S2[7], wb[7], a1);
        a2 = fmaf(S2[8], wb[8], a2);  a3 = fmaf(S2[9], wb[9], a3);
        const float hn = fmaxf((a0 + a1) + (a2 + a3), 0.f);
        #pragma unroll
        for (int k = 0; k < Hn; ++k) S1[k] = rlane(hn, k);        // h1(t)
        if (commitS2) {
            #pragma unroll
            for (int k = 0; k < Hn; ++k) S2[k] = rlane(hn, 16 + k); // h2(t-1)
        }
        if (doZ) zsum = zfrom(xv[q ^ 1]);   // z(t+1) from x(t+1), loaded last iter
        if (xr) {
            const v2f* xp = (const v2f*)xr; // uniform addr -> broadcast ds_read
            #pragma unroll
            for (int p = 0; p < 11; ++p) xv[q][p] = xp[p];  // x(t+2)
        }
    };

    // ---- i = 0 (no h2 commit: keep S2 = 0 for iter 1) ----
    iter(0, chunkA + 2 * Fn, true, false);

    // ---- i = 1..29 (finish chunk 0 reads: x(3)..x(31)) ----
    {
        const float* rp = chunkA + 3 * Fn;
        #pragma unroll 1
        for (int pp = 0; pp < 14; ++pp) {
            iter(1, rp,      true, true);
            iter(0, rp + Fn, true, true);
            rp += 2 * Fn;
        }
        iter(1, rp, true, true);   // i = 29, reads x(31)
    }

    // ---- main: 30 groups of 32 iters (i = 30..989), 2 groups per pass ----
    #pragma unroll 1
    for (int k = 0; k < 30; k += 2) {
        asm volatile("s_waitcnt vmcnt(0)" ::: "memory");
        stage(k + 2, chunkA);                 // even chunk -> A
        {
            const float* rp = chunkB;         // read chunk k+1 (odd)
            #pragma unroll 1
            for (int s = 0; s < 16; ++s) {
                iter(0, rp,      true, true);
                iter(1, rp + Fn, true, true);
                rp += 2 * Fn;
            }
        }
        asm volatile("s_waitcnt vmcnt(0)" ::: "memory");
        stage(k + 3, chunkB);                 // odd chunk -> B
        {
            const float* rp = chunkA;         // read chunk k+2 (even)
            #pragma unroll 1
            for (int s = 0; s < 16; ++s) {
                iter(0, rp,      true, true);
                iter(1, rp + Fn, true, true);
                rp += 2 * Fn;
            }
        }
    }

    // ---- tail: i = 990..999 read chunk 31 (slot B), then i = 1000 ----
    asm volatile("s_waitcnt vmcnt(0)" ::: "memory");
    {
        const float* rp = chunkB;
        #pragma unroll 1
        for (int s = 0; s < 5; ++s) {
            iter(0, rp,      true, true);
            iter(1, rp + Fn, true, true);
            rp += 2 * Fn;
        }
        iter(0, nullptr, false, true);   // i = 1000: commits S2 = h2(999)
    }

    // ---- head: out[b,:] = h2(999) @ w_lin.T + b_lin (h2 already >= 0) ----
    const int jc = (lane < Cn) ? lane : 0;
    float o = b_lin[jc];
    #pragma unroll
    for (int k = 0; k < Hn; ++k) o = fmaf(S2[k], w_lin[jc * Hn + k], o);
    if (lane < Cn) out[b * Cn + lane] = o;
}

} // namespace

extern "C" void kernel_launch(void* const* d_in, const int* in_sizes, int n_in,
                              void* d_out, int out_size, void* d_ws, size_t ws_size,
                              hipStream_t stream) {
    const float* x     = (const float*)d_in[0];
    const float* w_ih0 = (const float*)d_in[1];
    const float* w_hh0 = (const float*)d_in[2];
    const float* b_ih0 = (const float*)d_in[3];
    const float* b_hh0 = (const float*)d_in[4];
    const float* w_ih1 = (const float*)d_in[5];
    const float* w_hh1 = (const float*)d_in[6];
    const float* b_ih1 = (const float*)d_in[7];
    const float* b_hh1 = (const float*)d_in[8];
    const float* w_lin = (const float*)d_in[9];
    const float* b_lin = (const float*)d_in[10];
    float* out = (float*)d_out;

    // one batch per 64-thread block: 1024 waves -> every SIMD on the chip
    rnn_fat<<<dim3(1024), dim3(64), 0, stream>>>(
        x, w_ih0, w_hh0, b_ih0, b_hh0,
        w_ih1, w_hh1, b_ih1, b_hh1, w_lin, b_lin, out);
}

// Round 5
// 149.727 us; speedup vs baseline: 1.2269x; 1.1027x over previous
//
#include <hip/hip_runtime.h>

typedef float v2f __attribute__((ext_vector_type(2)));

namespace {

constexpr int Tn = 1000, Fn = 22, Hn = 10, Cn = 4;
constexpr int ROWB = Tn * Fn * 4;        // 88000 bytes per batch row
constexpr int CH_STEPS = 32;             // time steps per staged chunk
constexpr int CH_FLOATS = CH_STEPS * Fn; // 704 floats = 2816 B = 11 x 256 B
constexpr int CH_BYTES = CH_FLOATS * 4;
constexpr int NSTAGE = CH_BYTES / 256;   // 11 global_load_lds per chunk

__device__ __forceinline__ v2f mk2(float a, float b) { v2f r; r.x = a; r.y = b; return r; }
__device__ __forceinline__ v2f fma2(v2f a, v2f b, v2f c) { return __builtin_elementwise_fma(a, b, c); }
__device__ __forceinline__ float rlane(float v, int l) {
    return __uint_as_float(__builtin_amdgcn_readlane(__float_as_uint(v), l));
}
__device__ __forceinline__ void gld_lds4(const float* g, float* l) {
    __builtin_amdgcn_global_load_lds(
        (const __attribute__((address_space(1))) unsigned int*)g,
        (__attribute__((address_space(3))) unsigned int*)l, 4, 0, 0);
}

__global__ __launch_bounds__(64, 1) void rnn_fat(
    const float* __restrict__ x,
    const float* __restrict__ w_ih0, const float* __restrict__ w_hh0,
    const float* __restrict__ b_ih0, const float* __restrict__ b_hh0,
    const float* __restrict__ w_ih1, const float* __restrict__ w_hh1,
    const float* __restrict__ b_ih1, const float* __restrict__ b_hh1,
    const float* __restrict__ w_lin, const float* __restrict__ b_lin,
    float* __restrict__ out)
{
    // two DISTINCT LDS objects so LDS-DMA alias tracking never chains a
    // ds_read wait onto the chunk currently being DMA-staged.
    __shared__ __align__(16) float chunkA[CH_FLOATS];
    __shared__ __align__(16) float chunkB[CH_FLOATS];

    const int lane = threadIdx.x;          // one wave per block, one BATCH per wave
    const int b    = blockIdx.x;
    const bool isL1 = lane < Hn;                       // lanes 0..9  : layer-1 neurons
    const bool isL2 = (lane >= 16) && (lane < 16 + Hn);// lanes 16..25: layer-2 neurons
    const int j1 = isL1 ? lane : 0;
    const int j2 = isL2 ? (lane - 16) : 0;

    const float* __restrict__ xrow = x + (size_t)b * (Tn * Fn);

    // ---- per-lane weights ----
    v2f wih0p[11];
    #pragma unroll
    for (int p = 0; p < 11; ++p)
        wih0p[p] = mk2(w_ih0[j1 * Fn + 2 * p], w_ih0[j1 * Fn + 2 * p + 1]);
    const float* pa = isL1 ? (w_hh0 + j1 * Hn) : (w_ih1 + j2 * Hn);
    float wa[Hn], wb[Hn];
    #pragma unroll
    for (int k = 0; k < Hn; ++k) wa[k] = pa[k];
    #pragma unroll
    for (int k = 0; k < Hn; ++k) wb[k] = isL2 ? w_hh1[j2 * Hn + k] : 0.f;
    const float bias1 = b_ih0[j1] + b_hh0[j1];
    const float bias2 = b_ih1[j2] + b_hh1[j2];
    const v2f bz = mk2(bias1, 0.f);

    // ---- chunk staging: global -> LDS, 11 x 256B, row-end clamped ----
    auto stage = [&](int c, float* dst) {
        const float* src = xrow + c * CH_FLOATS;
        #pragma unroll
        for (int k = 0; k < NSTAGE; ++k) {
            const int off = c * CH_BYTES + k * 256;
            if (off + 256 <= ROWB) {
                gld_lds4(src + k * 64 + lane, dst + k * 64);
            } else if (off < ROWB) {
                if (lane * 4 < ROWB - off) gld_lds4(src + k * 64 + lane, dst + k * 64);
            }
        }
    };
    stage(0, chunkA);   // chunk 0: t = 0..31

    // ---- x(0), x(1) direct (uniform-address global loads) ----
    v2f xv[2][11];
    v2f t0[11];
    #pragma unroll
    for (int p = 0; p < 11; ++p) t0[p] = ((const v2f*)xrow)[p];
    #pragma unroll
    for (int p = 0; p < 11; ++p) xv[1][p] = ((const v2f*)(xrow + Fn))[p];

    auto zfrom = [&](const v2f* xp) -> float {
        v2f zA = fma2(xp[0], wih0p[0], bz);
        v2f zB = xp[1] * wih0p[1];
        zA = fma2(xp[2], wih0p[2], zA);   zB = fma2(xp[3], wih0p[3], zB);
        zA = fma2(xp[4], wih0p[4], zA);   zB = fma2(xp[5], wih0p[5], zB);
        zA = fma2(xp[6], wih0p[6], zA);   zB = fma2(xp[7], wih0p[7], zB);
        zA = fma2(xp[8], wih0p[8], zA);   zB = fma2(xp[9], wih0p[9], zB);
        zA = fma2(xp[10], wih0p[10], zA);
        return (zA.x + zB.x) + (zA.y + zB.y);
    };

    float zsum = zfrom(t0);   // z(0), valid on L1 lanes

    // h-state, wave-uniform (SGPRs via readlane): S1 = h1(t-1), S2 = h2(t-2)
    float S1[Hn], S2[Hn];
    #pragma unroll
    for (int k = 0; k < Hn; ++k) { S1[k] = 0.f; S2[k] = 0.f; }

    asm volatile("s_waitcnt vmcnt(0)" ::: "memory");   // chunk 0 (and x0/x1) ready
    stage(1, chunkB);                                  // chunk 1: t = 32..63

    // ---- one iteration: L1(t) on lanes 0-9, L2(t-1) on lanes 16-25 ----
    // REORDERED vs round 4: x(t+2) ds_reads issued at the TOP so the load->use
    // gap for zcomp is a full iteration (~150cy) instead of ~50cy.
    //  q: xv set written by this iter (x(t+2));  xr: its LDS addr (null = skip)
    auto iter = [&](int q, const float* xr, bool doZ, bool commitS2) {
        // (1) issue ds_reads for x(t+2) first; consumed by zcomp NEXT iter
        if (xr) {
            const v2f* xp = (const v2f*)xr; // uniform addr -> broadcast ds_read
            #pragma unroll
            for (int p = 0; p < 11; ++p) xv[q][p] = xp[p];
        }

        // (2) dot: L1(t) and L2(t-1) in one uniform stream
        float base = isL1 ? zsum : bias2;
        float a0 = fmaf(S1[0], wa[0], base);
        float a1 = S1[1] * wa[1];
        float a2 = S1[2] * wa[2];
        float a3 = S1[3] * wa[3];
        a0 = fmaf(S1[4], wa[4], a0);  a1 = fmaf(S1[5], wa[5], a1);
        a2 = fmaf(S1[6], wa[6], a2);  a3 = fmaf(S1[7], wa[7], a3);
        a0 = fmaf(S1[8], wa[8], a0);  a1 = fmaf(S1[9], wa[9], a1);
        a2 = fmaf(S2[0], wb[0], a2);  a3 = fmaf(S2[1], wb[1], a3);
        a0 = fmaf(S2[2], wb[2], a0);  a1 = fmaf(S2[3], wb[3], a1);
        a2 = fmaf(S2[4], wb[4], a2);  a3 = fmaf(S2[5], wb[5], a3);
        a0 = fmaf(S2[6], wb[6], a0);  a1 = fmaf(S2[7], wb[7], a1);
        a2 = fmaf(S2[8], wb[8], a2);  a3 = fmaf(S2[9], wb[9], a3);
        const float hn = fmaxf((a0 + a1) + (a2 + a3), 0.f);

        // (3) broadcast via readlane (VALU, no LDS round-trip)
        #pragma unroll
        for (int k = 0; k < Hn; ++k) S1[k] = rlane(hn, k);        // h1(t)
        if (commitS2) {
            #pragma unroll
            for (int k = 0; k < Hn; ++k) S2[k] = rlane(hn, 16 + k); // h2(t-1)
        }

        // (4) z(t+1) from x(t+1), loaded at the TOP of the previous iter
        if (doZ) zsum = zfrom(xv[q ^ 1]);
    };

    // ---- i = 0 (no h2 commit: keep S2 = 0 for iter 1) ----
    iter(0, chunkA + 2 * Fn, true, false);

    // ---- i = 1..29 (finish chunk 0 reads: x(3)..x(31)) ----
    {
        const float* rp = chunkA + 3 * Fn;
        #pragma unroll 1
        for (int pp = 0; pp < 14; ++pp) {
            iter(1, rp,      true, true);
            iter(0, rp + Fn, true, true);
            rp += 2 * Fn;
        }
        iter(1, rp, true, true);   // i = 29, reads x(31)
    }

    // ---- main: 30 groups of 32 iters (i = 30..989), 2 groups per pass ----
    #pragma unroll 1
    for (int k = 0; k < 30; k += 2) {
        asm volatile("s_waitcnt vmcnt(0)" ::: "memory");
        stage(k + 2, chunkA);                 // even chunk -> A
        {
            const float* rp = chunkB;         // read chunk k+1 (odd)
            #pragma unroll 1
            for (int s = 0; s < 16; ++s) {
                iter(0, rp,      true, true);
                iter(1, rp + Fn, true, true);
                rp += 2 * Fn;
            }
        }
        asm volatile("s_waitcnt vmcnt(0)" ::: "memory");
        stage(k + 3, chunkB);                 // odd chunk -> B
        {
            const float* rp = chunkA;         // read chunk k+2 (even)
            #pragma unroll 1
            for (int s = 0; s < 16; ++s) {
                iter(0, rp,      true, true);
                iter(1, rp + Fn, true, true);
                rp += 2 * Fn;
            }
        }
    }

    // ---- tail: i = 990..999 read chunk 31 (slot B), then commit iter ----
    asm volatile("s_waitcnt vmcnt(0)" ::: "memory");
    {
        const float* rp = chunkB;
        #pragma unroll 1
        for (int s = 0; s < 5; ++s) {
            iter(0, rp,      true, true);
            iter(1, rp + Fn, true, true);
            rp += 2 * Fn;
        }
        iter(0, nullptr, false, true);   // i = 1000: commits S2 = h2(999)
    }

    // ---- head: out[b,:] = h2(999) @ w_lin.T + b_lin (h2 already >= 0) ----
    const int jc = (lane < Cn) ? lane : 0;
    float o = b_lin[jc];
    #pragma unroll
    for (int k = 0; k < Hn; ++k) o = fmaf(S2[k], w_lin[jc * Hn + k], o);
    if (lane < Cn) out[b * Cn + lane] = o;
}

} // namespace

extern "C" void kernel_launch(void* const* d_in, const int* in_sizes, int n_in,
                              void* d_out, int out_size, void* d_ws, size_t ws_size,
                              hipStream_t stream) {
    const float* x     = (const float*)d_in[0];
    const float* w_ih0 = (const float*)d_in[1];
    const float* w_hh0 = (const float*)d_in[2];
    const float* b_ih0 = (const float*)d_in[3];
    const float* b_hh0 = (const float*)d_in[4];
    const float* w_ih1 = (const float*)d_in[5];
    const float* w_hh1 = (const float*)d_in[6];
    const float* b_ih1 = (const float*)d_in[7];
    const float* b_hh1 = (const float*)d_in[8];
    const float* w_lin = (const float*)d_in[9];
    const float* b_lin = (const float*)d_in[10];
    float* out = (float*)d_out;

    // one batch per 64-thread block: 1024 waves -> every SIMD on the chip
    rnn_fat<<<dim3(1024), dim3(64), 0, stream>>>(
        x, w_ih0, w_hh0, b_ih0, b_hh0,
        w_ih1, w_hh1, b_ih1, b_hh1, w_lin, b_lin, out);
}

// Round 6
// 116.680 us; speedup vs baseline: 1.5744x; 1.2832x over previous
//
#include <hip/hip_runtime.h>

typedef float v2f __attribute__((ext_vector_type(2)));

namespace {

constexpr int Tn = 1000, Fn = 22, Hn = 10, Cn = 4;
constexpr int ROWB = Tn * Fn * 4;     // 88000 B per batch row
constexpr int CHF  = 32 * Fn;         // 704 floats per 32-step chunk
constexpr int CHB  = CHF * 4;         // 2816 B = 11 x 256 B

__device__ __forceinline__ v2f mk2(float a, float b) { v2f r; r.x=a; r.y=b; return r; }
__device__ __forceinline__ v2f fma2(v2f a, v2f b, v2f c) { return __builtin_elementwise_fma(a,b,c); }
__device__ __forceinline__ float rlane(float v, int l) {
    return __uint_as_float(__builtin_amdgcn_readlane(__float_as_uint(v), l));
}
__device__ __forceinline__ void gld_lds4(const float* g, float* l) {
    __builtin_amdgcn_global_load_lds(
        (const __attribute__((address_space(1))) unsigned int*)g,
        (__attribute__((address_space(3))) unsigned int*)l, 4, 0, 0);
}
__device__ __forceinline__ void sfence() { __builtin_amdgcn_sched_barrier(0); }

__global__ __launch_bounds__(64, 1) void rnn_fat2(
    const float* __restrict__ x,
    const float* __restrict__ w_ih0, const float* __restrict__ w_hh0,
    const float* __restrict__ b_ih0, const float* __restrict__ b_hh0,
    const float* __restrict__ w_ih1, const float* __restrict__ w_hh1,
    const float* __restrict__ b_ih1, const float* __restrict__ b_hh1,
    const float* __restrict__ w_lin, const float* __restrict__ b_lin,
    float* __restrict__ out)
{
    __shared__ __align__(16) float ch[2][CHF];   // chunk c -> ch[c&1]

    const int lane = threadIdx.x;     // one wave per block, one batch per wave
    const int b    = blockIdx.x;
    const int half = lane >> 5;       // 0: even-step data, 1: odd-step data
    const int l31  = lane & 31;

    const int jz = (l31 < Hn) ? l31 : 0;                       // z / L1 row
    const bool isl2 = (l31 >= 16) && (l31 < 16 + Hn);
    const int j2 = isl2 ? (l31 - 16) : 0;

    // per-lane weights: L1-side lanes (l31<16) get w_hh0; L2-side get w_ih1/w_hh1
    const float* pwa = (l31 < 16) ? (w_hh0 + jz * Hn) : (w_ih1 + j2 * Hn);
    float wa[Hn], wb[Hn];
    #pragma unroll
    for (int k = 0; k < Hn; ++k) wa[k] = pwa[k];
    #pragma unroll
    for (int k = 0; k < Hn; ++k) wb[k] = isl2 ? w_hh1[j2 * Hn + k] : 0.f;
    v2f wih0p[11];
    #pragma unroll
    for (int p = 0; p < 11; ++p)
        wih0p[p] = mk2(w_ih0[jz * Fn + 2*p], w_ih0[jz * Fn + 2*p + 1]);
    const float bias1  = b_ih0[jz] + b_hh0[jz];
    const float bias2v = b_ih1[j2] + b_hh1[j2];
    const v2f bz2 = mk2(bias1, 0.f);

    const bool mL = (lane < Hn);                    // z-holders, even steps
    const bool mU = (lane >= 32) && (lane < 32+Hn); // z-holders, odd steps

    const float* __restrict__ xrow = x + (size_t)b * (Tn * Fn);

    // ---- DMA staging: chunk c (32 steps) -> ch[c&1] ----
    auto stage = [&](int c) {
        float* dst = ch[c & 1];
        const float* src = xrow + c * CHF;
        if (c < 31) {
            #pragma unroll
            for (int k = 0; k < 11; ++k) gld_lds4(src + k*64 + lane, dst + k*64);
        } else {   // chunk 31: 704 valid bytes = 2.75 x 256
            gld_lds4(src + lane, dst);
            gld_lds4(src + 64 + lane, dst + 64);
            if (lane < 48) gld_lds4(src + 128 + lane, dst + 128);
        }
    };
    stage(0); stage(1);

    // ---- direct global x for pairs 0,1 (per-half: lower x(2p), upper x(2p+1)) ----
    v2f xd[11], xv0[11], xv1[11];
    {
        const float* r01 = xrow + half * Fn;
        #pragma unroll
        for (int p = 0; p < 11; ++p) xd[p] = ((const v2f*)r01)[p];
        const float* r23 = xrow + (2 + half) * Fn;
        #pragma unroll
        for (int p = 0; p < 11; ++p) xv0[p] = ((const v2f*)r23)[p];
    }

    // z-pair: 11 pk-FMA single chain (4cy cadence covers the dep latency)
    auto zc = [&](const v2f* xp) -> float {
        v2f z = fma2(xp[0], wih0p[0], bz2);
        #pragma unroll
        for (int p = 1; p < 11; ++p) z = fma2(xp[p], wih0p[p], z);
        return z.x + z.y;
    };

    // LDS pointer for pair P (steps 2P, 2P+1), this lane's half
    auto pairptr = [&](int P) -> const float* {
        return &ch[(P >> 4) & 1][(P & 15) * 44 + half * 22];
    };
    auto loadxv = [&](v2f* dst, const float* rp) {
        #pragma unroll
        for (int p = 0; p < 11; ++p) dst[p] = ((const v2f*)rp)[p];
        sfence();   // pin the ds_read issue point (keep 2-step slack)
    };

    float S1[Hn], S2[Hn];   // wave-uniform h1(t-1), h2(t-2) in SGPRs
    #pragma unroll
    for (int k = 0; k < Hn; ++k) { S1[k] = 0.f; S2[k] = 0.f; }

    asm volatile("s_waitcnt vmcnt(0)" ::: "memory");  // chunks 0,1 + direct x ready
    float zA = zc(xd);    // pair 0: z(0) on lanes 0-9, z(1) on lanes 32-41
    float zB;

    // one time step: L1(t) & L2(t-1), single shared instruction stream.
    // up=false: dot lanes 0-25, readlane 0/16;  up=true: lanes 32-57, readlane 32/48.
    auto dostep = [&](bool up, float z, bool commit2) {
        const float base = (up ? mU : mL) ? z : bias2v;
        float a = fmaf(S1[0], wa[0], base);
        float c = S1[1] * wa[1];
        a = fmaf(S1[2], wa[2], a);  c = fmaf(S1[3], wa[3], c);
        a = fmaf(S1[4], wa[4], a);  c = fmaf(S1[5], wa[5], c);
        a = fmaf(S1[6], wa[6], a);  c = fmaf(S1[7], wa[7], c);
        a = fmaf(S1[8], wa[8], a);  c = fmaf(S1[9], wa[9], c);
        a = fmaf(S2[0], wb[0], a);  c = fmaf(S2[1], wb[1], c);
        a = fmaf(S2[2], wb[2], a);  c = fmaf(S2[3], wb[3], c);
        a = fmaf(S2[4], wb[4], a);  c = fmaf(S2[5], wb[5], c);
        a = fmaf(S2[6], wb[6], a);  c = fmaf(S2[7], wb[7], c);
        a = fmaf(S2[8], wb[8], a);  c = fmaf(S2[9], wb[9], c);
        const float hn = fmaxf(a + c, 0.f);
        if (!up) {
            #pragma unroll
            for (int k = 0; k < Hn; ++k) S1[k] = rlane(hn, k);
            if (commit2) {
                #pragma unroll
                for (int k = 0; k < Hn; ++k) S2[k] = rlane(hn, 16 + k);
            }
        } else {
            #pragma unroll
            for (int k = 0; k < Hn; ++k) S1[k] = rlane(hn, 32 + k);
            if (commit2) {
                #pragma unroll
                for (int k = 0; k < Hn; ++k) S2[k] = rlane(hn, 48 + k);
            }
        }
    };

    // macro = 4 steps t=4m..4m+3: {L0(zA), U0(zA), L1(zB), U1(zB)}
    //  L0: load xv1 <- pair 2m+2 ; zB = zc(xv0)   [pair 2m+1]
    //  L1: load xv0 <- pair 2m+3 ; zA = zc(xv1)   [pair 2m+2]
    auto MACRO = [&](int m, bool s2_0, bool ld0, bool ld1, bool z1) {
        if (ld0) loadxv(xv1, pairptr(2*m + 2));
        dostep(false, zA, s2_0);
        zB = zc(xv0);
        dostep(true, zA, true);
        if (ld1) loadxv(xv0, pairptr(2*m + 3));
        dostep(false, zB, true);
        if (z1) zA = zc(xv1);
        dostep(true, zB, true);
    };

    // m=0: no S2 commit at t=0 (h2(-1) must stay 0 for t=1)
    MACRO(0, false, true, true, true);

    #pragma unroll 1
    for (int m = 1; m < 249; ++m) {
        if ((m & 7) == 7) {     // before macro 8b+7: chunk b+1 needed at its L1
            asm volatile("s_waitcnt vmcnt(0)" ::: "memory");
            const int c = (m >> 3) + 2;
            if (c <= 31) stage(c);
        }
        MACRO(m, true, true, true, true);
    }
    // m=249 (t=996..999): no loads, no zc@L1 (would be pair 500)
    MACRO(249, true, false, false, false);

    // ---- final: h2(999) = relu(b2 + W_ih1 h1(999) + W_hh1 h2(998)), lanes 16-25 ----
    {
        float a = fmaf(S1[0], wa[0], bias2v);
        float c = S1[1] * wa[1];
        a = fmaf(S1[2], wa[2], a);  c = fmaf(S1[3], wa[3], c);
        a = fmaf(S1[4], wa[4], a);  c = fmaf(S1[5], wa[5], c);
        a = fmaf(S1[6], wa[6], a);  c = fmaf(S1[7], wa[7], c);
        a = fmaf(S1[8], wa[8], a);  c = fmaf(S1[9], wa[9], c);
        a = fmaf(S2[0], wb[0], a);  c = fmaf(S2[1], wb[1], c);
        a = fmaf(S2[2], wb[2], a);  c = fmaf(S2[3], wb[3], c);
        a = fmaf(S2[4], wb[4], a);  c = fmaf(S2[5], wb[5], c);
        a = fmaf(S2[6], wb[6], a);  c = fmaf(S2[7], wb[7], c);
        a = fmaf(S2[8], wb[8], a);  c = fmaf(S2[9], wb[9], c);
        const float hn = fmaxf(a + c, 0.f);
        #pragma unroll
        for (int k = 0; k < Hn; ++k) S2[k] = rlane(hn, 16 + k);
    }

    // ---- head: out[b,:] = h2(999) @ w_lin.T + b_lin ----
    const int jc = (lane < Cn) ? lane : 0;
    float o = b_lin[jc];
    #pragma unroll
    for (int k = 0; k < Hn; ++k) o = fmaf(S2[k], w_lin[jc * Hn + k], o);
    if (lane < Cn) out[b * Cn + lane] = o;
}

} // namespace

extern "C" void kernel_launch(void* const* d_in, const int* in_sizes, int n_in,
                              void* d_out, int out_size, void* d_ws, size_t ws_size,
                              hipStream_t stream) {
    const float* x     = (const float*)d_in[0];
    const float* w_ih0 = (const float*)d_in[1];
    const float* w_hh0 = (const float*)d_in[2];
    const float* b_ih0 = (const float*)d_in[3];
    const float* b_hh0 = (const float*)d_in[4];
    const float* w_ih1 = (const float*)d_in[5];
    const float* w_hh1 = (const float*)d_in[6];
    const float* b_ih1 = (const float*)d_in[7];
    const float* b_hh1 = (const float*)d_in[8];
    const float* w_lin = (const float*)d_in[9];
    const float* b_lin = (const float*)d_in[10];
    float* out = (float*)d_out;

    // one batch per 64-thread block: 1024 waves, 1 per SIMD
    rnn_fat2<<<dim3(1024), dim3(64), 0, stream>>>(
        x, w_ih0, w_hh0, b_ih0, b_hh0,
        w_ih1, w_hh1, b_ih1, b_hh1, w_lin, b_lin, out);
}